// Round 5
// baseline (492.428 us; speedup 1.0000x reference)
//
#include <hip/hip_runtime.h>
#include <hip/hip_bf16.h>

#define B_SZ 8192
#define KNB 16
#define BK 131072
#define ED 256

typedef __attribute__((ext_vector_type(8))) short short8v;
typedef __attribute__((ext_vector_type(4))) float floatx4;

static __device__ __forceinline__ unsigned short f2bf(float f) {
  unsigned int u = __float_as_uint(f);
  u = (u + 0x7FFFu + ((u >> 16) & 1u)) >> 16;
  return (unsigned short)u;
}
static __device__ __forceinline__ float bf2f(unsigned short u) {
  return __uint_as_float(((unsigned int)u) << 16);
}
static __device__ __forceinline__ float gelu_erf(float x) {
  return 0.5f * x * (1.0f + erff(x * 0.70710678118654752f));
}
// gelu via odd Taylor of erf(x/sqrt(2)); exact to ~1e-9 for |x|<0.5 (FF2/FF3 have |x|<0.15)
static __device__ __forceinline__ float gelu_poly(float x) {
  float t = x * x;
  float p = fmaf(t, fmaf(t, fmaf(t, fmaf(t, 2.8935185185e-4f, -2.9761904762e-3f),
                                 2.5e-2f), -1.6666666667e-1f), 1.0f);
  return 0.5f * x * fmaf(0.79788456080286536f * x, p, 1.0f);
}

#define MFMA(a, b, c) __builtin_amdgcn_mfma_f32_16x16x32_bf16((a), (b), (c), 0, 0, 0)

// async global->LDS, 16B per lane, dest = wave-uniform base + lane*16
static __device__ __forceinline__ void gll16(const void* g, void* l) {
  __builtin_amdgcn_global_load_lds(
      (const __attribute__((address_space(1))) unsigned int*)g,
      (__attribute__((address_space(3))) unsigned int*)l, 16, 0, 0);
}

// ---------------- prep: W[K][N] f32 -> WT[N][K] bf16 ----------------
__global__ void wt_kernel(const float* __restrict__ W, unsigned short* __restrict__ WT,
                          int K, int N) {
  int idx = blockIdx.x * 256 + threadIdx.x;
  if (idx >= K * N) return;
  int n = idx / K, k = idx - n * K;
  WT[idx] = f2bf(W[(size_t)k * N + n]);
}

// ---------------- prep: W (256 k-rows x ncols, f32 row-major ld=ldw) -> MFMA-fragment order --
// frag f = ctile*8 + kk (ctile over ncols/16, kk 0..7 over K=256).
// Within frag: short index = lane*8 + i, element = W[k = kk*32 + (lane>>4)*8 + i]
//                                            [col = ctile*16 + (lane&15)].
// A wave's ds_read_b128 of one frag is then a contiguous 1 KB: conflict-free.
__global__ void wf_kernel(const float* __restrict__ W, unsigned short* __restrict__ WF,
                          int ldw) {
  int idx = blockIdx.x * 256 + threadIdx.x;   // ncols*256 elements
  int f = idx >> 9;          // frag id
  int w = idx & 511;         // short index within frag
  int ln = w >> 3, i = w & 7;
  int ctile = f >> 3, kk = f & 7;
  int col = ctile * 16 + (ln & 15);
  int k = kk * 32 + (ln >> 4) * 8 + i;
  WF[idx] = f2bf(W[(size_t)k * ldw + col]);
}

// ---------------- K1: FF1 (gathered input) -> E (bf16), M (bf16) ----------------
__global__ __launch_bounds__(256) void k1_kernel(
    const float* __restrict__ self_obs, const float* __restrict__ obs,
    const unsigned short* __restrict__ We1T, const float* __restrict__ be1,
    const unsigned short* __restrict__ We2T, const float* __restrict__ be2,
    unsigned short* __restrict__ E, unsigned short* __restrict__ M) {
  __shared__ unsigned short Xt[64][136];   // 64 x 128 bf16, +8 pad
  __shared__ unsigned short Ht[64][136];   // 64 x 128 bf16 hidden chunk
  const int tid = threadIdx.x;
  const int wave = tid >> 6, lane = tid & 63, g = lane >> 4, r = lane & 15;
  const int row0 = blockIdx.x * 64;

  // stage gathered X tile, f32 -> bf16
#pragma unroll
  for (int p = 0; p < 8; ++p) {
    int e4 = (p * 256 + tid) * 4;
    int i = e4 >> 7, c = e4 & 127;
    int gi = row0 + i;
    const float* src;
    if (c < 64) src = self_obs + (size_t)(gi & (B_SZ - 1)) * 64 + c;
    else        src = obs + (size_t)(gi >> 4) * 1088 + 64 + (gi & 15) * 64 + (c - 64);
    float4 v = *(const float4*)src;
    ushort4 w;
    w.x = f2bf(v.x); w.y = f2bf(v.y); w.z = f2bf(v.z); w.w = f2bf(v.w);
    *(ushort4*)&Xt[i][c] = w;
  }
  __syncthreads();

  floatx4 eacc[4][4];  // [rt][ct]
#pragma unroll
  for (int a = 0; a < 4; ++a)
#pragma unroll
    for (int c2 = 0; c2 < 4; ++c2) eacc[a][c2] = (floatx4)0.0f;

  for (int chunk = 0; chunk < 4; ++chunk) {
    const int hbase = chunk * 128;
    floatx4 hacc[2][4];  // [ctl][rt]
#pragma unroll
    for (int a = 0; a < 2; ++a)
#pragma unroll
      for (int c2 = 0; c2 < 4; ++c2) hacc[a][c2] = (floatx4)0.0f;

#pragma unroll
    for (int kk = 0; kk < 4; ++kk) {   // K = 128
      short8v afr[4];
#pragma unroll
      for (int rt = 0; rt < 4; ++rt)
        afr[rt] = *(const short8v*)&Xt[rt * 16 + r][kk * 32 + g * 8];
#pragma unroll
      for (int ctl = 0; ctl < 2; ++ctl) {
        int col = hbase + wave * 32 + ctl * 16 + r;
        short8v bfr = *(const short8v*)&We1T[(size_t)col * 128 + kk * 32 + g * 8];
#pragma unroll
        for (int rt = 0; rt < 4; ++rt) hacc[ctl][rt] = MFMA(afr[rt], bfr, hacc[ctl][rt]);
      }
    }
    // bias + gelu(erf) -> Ht
#pragma unroll
    for (int ctl = 0; ctl < 2; ++ctl) {
      int col = hbase + wave * 32 + ctl * 16 + r;
      float bias = be1[col];
#pragma unroll
      for (int rt = 0; rt < 4; ++rt)
#pragma unroll
        for (int q = 0; q < 4; ++q) {
          float h = gelu_erf(hacc[ctl][rt][q] + bias);
          Ht[rt * 16 + g * 4 + q][wave * 32 + ctl * 16 + r] = f2bf(h);
        }
    }
    __syncthreads();
    // layer2 partial: E += gelu(H) @ We2[hbase:hbase+128, :]
#pragma unroll
    for (int kk = 0; kk < 4; ++kk) {
      short8v afr[4];
#pragma unroll
      for (int rt = 0; rt < 4; ++rt)
        afr[rt] = *(const short8v*)&Ht[rt * 16 + r][kk * 32 + g * 8];
#pragma unroll
      for (int ct = 0; ct < 4; ++ct) {
        int col = wave * 64 + ct * 16 + r;
        short8v bfr = *(const short8v*)&We2T[(size_t)col * 512 + hbase + kk * 32 + g * 8];
#pragma unroll
        for (int rt = 0; rt < 4; ++rt) eacc[rt][ct] = MFMA(afr[rt], bfr, eacc[rt][ct]);
      }
    }
    __syncthreads();
  }

  // epilogue: +bias, store E (bf16), 16-row group mean -> M
#pragma unroll
  for (int ct = 0; ct < 4; ++ct) {
    int col = wave * 64 + ct * 16 + r;
    float bias = be2[col];
#pragma unroll
    for (int rt = 0; rt < 4; ++rt) {
      float msum = 0.f;
#pragma unroll
      for (int q = 0; q < 4; ++q) {
        float e = eacc[rt][ct][q] + bias;
        int row = rt * 16 + g * 4 + q;
        E[(size_t)(row0 + row) * ED + col] = f2bf(e);
        msum += e;
      }
      msum += __shfl_xor(msum, 16);
      msum += __shfl_xor(msum, 32);
      if (g == 0) {
        int b = (row0 >> 4) + rt;
        M[(size_t)b * ED + col] = f2bf(msum * 0.0625f);
      }
    }
  }
}

// ---------------- K2: MV = M @ Wa1_bot + ba1  (8192 x 2048 x 256), bf16 out ------
// Tile 128x256, BK=64, 8 waves (2x4), wave 64x64.
__global__ __launch_bounds__(512) void k2_mv(
    const unsigned short* __restrict__ M, const unsigned short* __restrict__ Wa1T,
    const float* __restrict__ ba1, unsigned short* __restrict__ MV) {
  __shared__ unsigned short Abuf[128 * 64];   // 16 KB
  __shared__ unsigned short Bbuf[256 * 64];   // 32 KB
  const int tid = threadIdx.x;
  const int wave = tid >> 6, lane = tid & 63, g = lane >> 4, r = lane & 15;
  const int wr = wave >> 2, wc = wave & 3;
  const int row0 = blockIdx.y * 128;
  const int col0 = blockIdx.x * 256;
  const int sr = lane >> 3, sc = lane & 7;
  const int swz = ((sc ^ sr) << 4);

  floatx4 acc[4][4];
#pragma unroll
  for (int a = 0; a < 4; ++a)
#pragma unroll
    for (int c2 = 0; c2 < 4; ++c2) acc[a][c2] = (floatx4)0.0f;

  for (int t = 0; t < 4; ++t) {
#pragma unroll
    for (int j = 0; j < 2; ++j) {
      int rowA = j * 64 + wave * 8 + sr;
      const char* src = (const char*)M + ((size_t)(row0 + rowA)) * 512 + t * 128 + swz;
      gll16(src, (char*)Abuf + (j * 512 + wave * 64) * 16);
    }
#pragma unroll
    for (int j = 0; j < 4; ++j) {
      int colB = j * 64 + wave * 8 + sr;
      // bottom half of Wa1T rows (k = 256..511 -> byte offset +512 of each 1KB col)
      const char* src = (const char*)Wa1T + ((size_t)(col0 + colB)) * 1024 + 512
                        + t * 128 + swz;
      gll16(src, (char*)Bbuf + (j * 512 + wave * 64) * 16);
    }
    __syncthreads();
#pragma unroll
    for (int kk = 0; kk < 2; ++kk) {
      const int off = (kk * 64 + g * 16) ^ ((r & 7) << 4);
      short8v afr[4], bfr[4];
#pragma unroll
      for (int rt = 0; rt < 4; ++rt)
        afr[rt] = *(const short8v*)((const char*)Abuf + (wr * 64 + rt * 16 + r) * 128 + off);
#pragma unroll
      for (int ct = 0; ct < 4; ++ct)
        bfr[ct] = *(const short8v*)((const char*)Bbuf + (wc * 64 + ct * 16 + r) * 128 + off);
#pragma unroll
      for (int rt = 0; rt < 4; ++rt)
#pragma unroll
        for (int ct = 0; ct < 4; ++ct) acc[rt][ct] = MFMA(afr[rt], bfr[ct], acc[rt][ct]);
    }
    __syncthreads();
  }

#pragma unroll
  for (int ct = 0; ct < 4; ++ct) {
    int col = col0 + wc * 64 + ct * 16 + r;
    float b1 = ba1[col];
#pragma unroll
    for (int rt = 0; rt < 4; ++rt)
#pragma unroll
      for (int q = 0; q < 4; ++q)
        MV[(size_t)(row0 + wr * 64 + rt * 16 + g * 4 + q) * 2048 + col] =
            f2bf(acc[rt][ct][q] + b1);
  }
}

// ---------------- K3 fused: logits + in-wave softmax + weighted value-FF1 -> G -----
// GROUPING (matches reference .repeat/.reshape semantics): softmax & final-sum groups
// are 16 CONSECUTIVE rows i of the neighbor-major array, i.e. {knb fixed, 16
// consecutive batch rows j}. Output row b = knb*512 + bid, group j = bid*16 + k.
// Assignment: block bid owns j = bid*16 + r (lane r = group member = MFMA N-dim);
// wave owns neighbor slots knb0 = wave*2, knb0+1. E rows i = knb*8192 + bid*16 + r
// (32 rows = 64 VGPR, 16-row contiguous spans) loaded ONCE -> E read once globally.
// mv row = i & 8191 = bid*16 + r: SAME for both knb slots -> one load serves both.
// Phase A (64 chunks over Wa1F): logits. In-wave softmax over r-lanes (= the group).
// Phase B (32 chunks over Wv1F): gelu(E@Wv1+bv1)*attn, 4-shuffle r-reduce -> G rows
// b0 = knb0*512+bid, b1 = b0+512. Pipeline: 4 x 16 KB bufs, 2-chunk barrier groups.
__global__ __launch_bounds__(512, 4) void k3_fused(
    const unsigned short* __restrict__ E, const unsigned short* __restrict__ MV,
    const unsigned short* __restrict__ Wa1F, const float* __restrict__ Wa2,
    const unsigned short* __restrict__ Wv1F, const float* __restrict__ bv1,
    unsigned short* __restrict__ G) {
  __shared__ char Bq[65536];   // 4 bufs x 16 frags x 1 KB
  const int tid = threadIdx.x;
  const int wave = tid >> 6, lane = tid & 63, g = lane >> 4, r = lane & 15;
  const int bid = blockIdx.x;          // 0..511
  const int knb0 = wave * 2;
  const int jr = bid * 16 + r;         // this lane's batch row within the group

  // ---- E preload: rows i = knb*8192 + jr, full K=256 ----
  short8v er0[8], er1[8];
  {
    const unsigned short* e0 = E + ((size_t)knb0 * 8192 + jr) * 256 + g * 8;
    const unsigned short* e1 = e0 + (size_t)8192 * 256;
#pragma unroll
    for (int kk = 0; kk < 8; ++kk) {
      er0[kk] = *(const short8v*)(e0 + kk * 32);
      er1[kk] = *(const short8v*)(e1 + kk * 32);
    }
  }

  // stage chunk c of WF into buf (c&3): 2 linear gll16 per wave
  auto STAGE = [&](const unsigned short* WF, int c) {
    char* dst = Bq + (c & 3) * 16384 + wave * 2048;
    const char* src = (const char*)WF + (size_t)c * 16384 + wave * 2048 + lane * 16;
    gll16(src, dst);
    gll16(src + 1024, dst + 1024);
  };

  const unsigned short* mvp = MV + (size_t)jr * 2048;  // per-lane (r-dependent)
  float lgp0 = 0.f, lgp1 = 0.f;

  auto CHUNK_A = [&](int c) {
    ushort4 mq[2];
    float4 w2[2];
#pragma unroll
    for (int ct = 0; ct < 2; ++ct) {
      mq[ct] = *(const ushort4*)(mvp + c * 32 + ct * 16 + g * 4);
      w2[ct] = *(const float4*)&Wa2[c * 32 + ct * 16 + g * 4];
    }
    floatx4 acc0[2], acc1[2];
    acc0[0] = (floatx4)0.0f; acc0[1] = (floatx4)0.0f;
    acc1[0] = (floatx4)0.0f; acc1[1] = (floatx4)0.0f;
    const char* bufb = Bq + (c & 3) * 16384;
#pragma unroll
    for (int kk = 0; kk < 8; ++kk) {
#pragma unroll
      for (int ct = 0; ct < 2; ++ct) {
        short8v a = *(const short8v*)(bufb + (ct * 8 + kk) * 1024 + lane * 16);
        acc0[ct] = MFMA(a, er0[kk], acc0[ct]);
        acc1[ct] = MFMA(a, er1[kk], acc1[ct]);
      }
    }
#pragma unroll
    for (int ct = 0; ct < 2; ++ct) {
      const float* wp = (const float*)&w2[ct];
      const unsigned short* mp = (const unsigned short*)&mq[ct];
#pragma unroll
      for (int q = 0; q < 4; ++q) {
        float mvv = bf2f(mp[q]);
        lgp0 = fmaf(gelu_poly(acc0[ct][q] + mvv), wp[q], lgp0);
        lgp1 = fmaf(gelu_poly(acc1[ct][q] + mvv), wp[q], lgp1);
      }
    }
  };

  float aw0 = 0.f, aw1 = 0.f;

  auto CHUNK_B = [&](int c) {
    float4 b1[2];
#pragma unroll
    for (int ct = 0; ct < 2; ++ct)
      b1[ct] = *(const float4*)&bv1[c * 32 + ct * 16 + g * 4];
    floatx4 acc0[2], acc1[2];
    acc0[0] = (floatx4)0.0f; acc0[1] = (floatx4)0.0f;
    acc1[0] = (floatx4)0.0f; acc1[1] = (floatx4)0.0f;
    const char* bufb = Bq + (c & 3) * 16384;
#pragma unroll
    for (int kk = 0; kk < 8; ++kk) {
#pragma unroll
      for (int ct = 0; ct < 2; ++ct) {
        short8v a = *(const short8v*)(bufb + (ct * 8 + kk) * 1024 + lane * 16);
        acc0[ct] = MFMA(a, er0[kk], acc0[ct]);
        acc1[ct] = MFMA(a, er1[kk], acc1[ct]);
      }
    }
#pragma unroll
    for (int ct = 0; ct < 2; ++ct) {
      const float* bp = (const float*)&b1[ct];
      ushort4 p0, p1;
      unsigned short* pp0 = (unsigned short*)&p0;
      unsigned short* pp1 = (unsigned short*)&p1;
#pragma unroll
      for (int q = 0; q < 4; ++q) {
        float v0 = gelu_poly(acc0[ct][q] + bp[q]) * aw0;
        float v1 = gelu_poly(acc1[ct][q] + bp[q]) * aw1;
        v0 += __shfl_xor(v0, 1); v0 += __shfl_xor(v0, 2);
        v0 += __shfl_xor(v0, 4); v0 += __shfl_xor(v0, 8);
        v1 += __shfl_xor(v1, 1); v1 += __shfl_xor(v1, 2);
        v1 += __shfl_xor(v1, 4); v1 += __shfl_xor(v1, 8);
        pp0[q] = f2bf(v0);
        pp1[q] = f2bf(v1);
      }
      if (r == 0) {
        size_t b0 = (size_t)(knb0 * 512 + bid);
        *(ushort4*)&G[b0 * 1024 + c * 32 + ct * 16 + g * 4] = p0;
        *(ushort4*)&G[(b0 + 512) * 1024 + c * 32 + ct * 16 + g * 4] = p1;
      }
    }
  };

  // ---- phase A: 64 chunks, 2-chunk groups ----
  STAGE(Wa1F, 0); STAGE(Wa1F, 1);
  __syncthreads();
  for (int gi = 0; gi < 31; ++gi) {
    const int c = gi * 2;
    STAGE(Wa1F, c + 2); STAGE(Wa1F, c + 3);
    CHUNK_A(c); CHUNK_A(c + 1);
    __syncthreads();
  }
  // last A group: stage phase-B chunks 0,1 (-> bufs 0,1; A reads bufs 2,3)
  STAGE(Wv1F, 0); STAGE(Wv1F, 1);
  CHUNK_A(62); CHUNK_A(63);
  __syncthreads();

  // ---- in-wave softmax over the r-lanes (the 16-consecutive-row group).
  // ba2 uniform -> drops out of softmax.
  lgp0 += __shfl_xor(lgp0, 16); lgp0 += __shfl_xor(lgp0, 32);
  lgp1 += __shfl_xor(lgp1, 16); lgp1 += __shfl_xor(lgp1, 32);
  float m0 = lgp0, m1 = lgp1;
  m0 = fmaxf(m0, __shfl_xor(m0, 1)); m0 = fmaxf(m0, __shfl_xor(m0, 2));
  m0 = fmaxf(m0, __shfl_xor(m0, 4)); m0 = fmaxf(m0, __shfl_xor(m0, 8));
  m1 = fmaxf(m1, __shfl_xor(m1, 1)); m1 = fmaxf(m1, __shfl_xor(m1, 2));
  m1 = fmaxf(m1, __shfl_xor(m1, 4)); m1 = fmaxf(m1, __shfl_xor(m1, 8));
  float e0 = expf(lgp0 - m0), e1 = expf(lgp1 - m1);
  float s0 = e0, s1 = e1;
  s0 += __shfl_xor(s0, 1); s0 += __shfl_xor(s0, 2);
  s0 += __shfl_xor(s0, 4); s0 += __shfl_xor(s0, 8);
  s1 += __shfl_xor(s1, 1); s1 += __shfl_xor(s1, 2);
  s1 += __shfl_xor(s1, 4); s1 += __shfl_xor(s1, 8);
  aw0 = e0 / s0;
  aw1 = e1 / s1;

  // ---- phase B: 32 chunks over Wv1F, same pipeline ----
  for (int gi = 0; gi < 16; ++gi) {
    const int c = gi * 2;
    if (gi < 15) { STAGE(Wv1F, c + 2); STAGE(Wv1F, c + 3); }
    CHUNK_B(c); CHUNK_B(c + 1);
    __syncthreads();
  }
}

// ---------------- K5b: out = G @ Wv2 + bv2  (8192 x 1024 x 256) ----------------
// Tile 64x128, BK=64, 4 waves (2x2), wave 32x64.
__global__ __launch_bounds__(256) void k5b_gemm(
    const unsigned short* __restrict__ G, const unsigned short* __restrict__ Wv2T,
    const float* __restrict__ bv2, float* __restrict__ out) {
  __shared__ unsigned short Abuf[64 * 64];    // 8 KB
  __shared__ unsigned short Bbuf[128 * 64];   // 16 KB
  const int tid = threadIdx.x;
  const int wave = tid >> 6, lane = tid & 63, g = lane >> 4, r = lane & 15;
  const int wr = wave >> 1, wc = wave & 1;
  const int col0 = blockIdx.x * 128;
  const int row0 = blockIdx.y * 64;
  const int sr = lane >> 3, sc = lane & 7;
  const int swz = ((sc ^ sr) << 4);

  floatx4 acc[2][4];
#pragma unroll
  for (int a = 0; a < 2; ++a)
#pragma unroll
    for (int c2 = 0; c2 < 4; ++c2) acc[a][c2] = (floatx4)0.0f;

  for (int t = 0; t < 16; ++t) {
#pragma unroll
    for (int j = 0; j < 2; ++j) {
      int rowA = j * 32 + wave * 8 + sr;
      const char* src = (const char*)G + ((size_t)(row0 + rowA)) * 2048 + t * 128 + swz;
      gll16(src, (char*)Abuf + (j * 256 + wave * 64) * 16);
    }
#pragma unroll
    for (int j = 0; j < 4; ++j) {
      int colB = j * 32 + wave * 8 + sr;
      const char* src = (const char*)Wv2T + ((size_t)(col0 + colB)) * 2048 + t * 128 + swz;
      gll16(src, (char*)Bbuf + (j * 256 + wave * 64) * 16);
    }
    __syncthreads();
#pragma unroll
    for (int kk = 0; kk < 2; ++kk) {
      const int off = (kk * 64 + g * 16) ^ ((r & 7) << 4);
      short8v afr[2], bfr[4];
#pragma unroll
      for (int rt = 0; rt < 2; ++rt)
        afr[rt] = *(const short8v*)((const char*)Abuf + (wr * 32 + rt * 16 + r) * 128 + off);
#pragma unroll
      for (int ct = 0; ct < 4; ++ct)
        bfr[ct] = *(const short8v*)((const char*)Bbuf + (wc * 64 + ct * 16 + r) * 128 + off);
#pragma unroll
      for (int rt = 0; rt < 2; ++rt)
#pragma unroll
        for (int ct = 0; ct < 4; ++ct) acc[rt][ct] = MFMA(afr[rt], bfr[ct], acc[rt][ct]);
    }
    __syncthreads();
  }

#pragma unroll
  for (int ct = 0; ct < 4; ++ct) {
    int col = col0 + wc * 64 + ct * 16 + r;
    float b = bv2[col];
#pragma unroll
    for (int rt = 0; rt < 2; ++rt)
#pragma unroll
      for (int q = 0; q < 4; ++q)
        out[(size_t)(row0 + wr * 32 + rt * 16 + g * 4 + q) * ED + col] =
            acc[rt][ct][q] + b;
  }
}

extern "C" void kernel_launch(void* const* d_in, const int* in_sizes, int n_in,
                              void* d_out, int out_size, void* d_ws, size_t ws_size,
                              hipStream_t stream) {
  const float* self_obs = (const float*)d_in[0];
  const float* obs = (const float*)d_in[1];
  const float* We1 = (const float*)d_in[2];
  const float* be1 = (const float*)d_in[3];
  const float* We2 = (const float*)d_in[4];
  const float* be2 = (const float*)d_in[5];
  const float* Wv1 = (const float*)d_in[6];
  const float* bv1 = (const float*)d_in[7];
  const float* Wv2 = (const float*)d_in[8];
  const float* bv2 = (const float*)d_in[9];
  const float* Wa1 = (const float*)d_in[10];
  const float* ba1 = (const float*)d_in[11];
  const float* Wa2 = (const float*)d_in[12];
  const float* ba2 = (const float*)d_in[13];
  float* out = (float*)d_out;
  (void)ba2;  // uniform over softmax axis -> drops out

  char* ws = (char*)d_ws;
  size_t off = 0;
  auto alloc = [&](size_t bytes) {
    char* p = ws + off;
    off += (bytes + 255) & ~(size_t)255;
    return p;
  };
  unsigned short* E    = (unsigned short*)alloc((size_t)BK * ED * 2);      // 64 MB
  unsigned short* M    = (unsigned short*)alloc((size_t)B_SZ * ED * 2);    // 4 MB
  unsigned short* MV   = (unsigned short*)alloc((size_t)B_SZ * 2048 * 2);  // 32 MB
  unsigned short* G    = (unsigned short*)alloc((size_t)B_SZ * 1024 * 2);  // 16 MB
  unsigned short* We1T = (unsigned short*)alloc(128 * 512 * 2);
  unsigned short* We2T = (unsigned short*)alloc(512 * 256 * 2);
  unsigned short* Wv2T = (unsigned short*)alloc(1024 * 256 * 2);
  unsigned short* Wa1T = (unsigned short*)alloc(512 * 2048 * 2);
  unsigned short* Wa1F = (unsigned short*)alloc(2048 * 256 * 2);           // 1 MB
  unsigned short* Wv1F = (unsigned short*)alloc(1024 * 256 * 2);           // 0.5 MB

  wt_kernel<<<(128 * 512 + 255) / 256, 256, 0, stream>>>(We1, We1T, 128, 512);
  wt_kernel<<<(512 * 256 + 255) / 256, 256, 0, stream>>>(We2, We2T, 512, 256);
  wt_kernel<<<(1024 * 256 + 255) / 256, 256, 0, stream>>>(Wv2, Wv2T, 1024, 256);
  wt_kernel<<<(512 * 2048 + 255) / 256, 256, 0, stream>>>(Wa1, Wa1T, 512, 2048);
  wf_kernel<<<2048, 256, 0, stream>>>(Wa1, Wa1F, 2048);   // top half k=0..255
  wf_kernel<<<1024, 256, 0, stream>>>(Wv1, Wv1F, 1024);

  k1_kernel<<<BK / 64, 256, 0, stream>>>(self_obs, obs, We1T, be1, We2T, be2, E, M);
  k2_mv<<<dim3(8, 64), 512, 0, stream>>>(M, Wa1T, ba1, MV);
  k3_fused<<<B_SZ / 16, 512, 0, stream>>>(E, MV, Wa1F, Wa2, Wv1F, bv1, G);
  k5b_gemm<<<dim3(2, 128), 256, 0, stream>>>(G, Wv2T, bv2, out);
}